// Round 12
// baseline (91.987 us; speedup 1.0000x reference)
//
#include <hip/hip_runtime.h>
#include <hip/hip_fp16.h>

#define KDIM 1024
#define DDIM 64
#define SPAT 32768
#define NVEC 65536
#define DSP  (DDIM * SPAT)          // 2097152
#define MARGIN 3.0e-4f              // bound(hi-only fp16 approx vs numpy-f32, two-sided) ~2e-4
#define ZPAD 68                     // floats; 16B-aligned rows, 4-bank stride => 2-way (free)
#define QCAP 384

typedef _Float16 half8 __attribute__((ext_vector_type(8)));
typedef float floatx4 __attribute__((ext_vector_type(4)));

__device__ __forceinline__ float opaque(float x) { asm volatile("" : "+v"(x)); return x; }

// sortable-uint transform for signed floats (monotone)
__device__ __forceinline__ unsigned int f2s(float x) {
    unsigned int u = __float_as_uint(x);
    return u ^ ((u >> 31) ? 0xffffffffu : 0x80000000u);
}
__device__ __forceinline__ float s2f(unsigned int u) {
    unsigned int v = u ^ ((u & 0x80000000u) ? 0x80000000u : 0xffffffffu);
    return __uint_as_float(v);
}

// Bitwise replica of np.add.reduce pairwise base case over fl(x[d]^2), d=0..63 (R3-proven)
__device__ __forceinline__ float np_sumsq64(const float* x) {
    float r8[8];
#pragma unroll
    for (int j = 0; j < 8; ++j) r8[j] = opaque(x[1 + j] * x[1 + j]);
#pragma unroll
    for (int i = 8; i < 56; i += 8) {
#pragma unroll
        for (int j = 0; j < 8; ++j) r8[j] += opaque(x[1 + i + j] * x[1 + i + j]);
    }
    float res = ((r8[0] + r8[1]) + (r8[2] + r8[3])) + ((r8[4] + r8[5]) + (r8[6] + r8[7]));
#pragma unroll
    for (int m = 57; m < 64; ++m) res += opaque(x[m] * x[m]);
    return opaque(x[0] * x[0]) + res;
}

// Bit-exact numpy-f32 distance, packed (distbits<<32)|k. fl(2z)*e == (2e)*z inside fma.
__device__ __forceinline__ unsigned long long exact_score(
    const float* zr, float snr, const float* __restrict__ emb,
    const float* h_lds, int k)
{
    const float* ep = emb + (size_t)k * DDIM;
    float acc = 0.f;
#pragma unroll
    for (int d = 0; d < DDIM; ++d)
        acc = fmaf(2.0f * ep[d], zr[d], acc);  // sgemm: sequential f32 FMA from 0, ascending d
    float tt   = snr + h_lds[k];               // fl(sn + h)
    float dist = tt - acc;                     // fl(t - 2 z.e)
    return ((unsigned long long)__float_as_uint(dist) << 32) | (unsigned int)k;
}

// K1: h = np-f32 ||e||^2, eh = fp16(e*1024)
__global__ void vq_prep_e(const float* __restrict__ emb, float* __restrict__ h,
                          __half* __restrict__ eh) {
    __shared__ float L[64 * ZPAD];
    const int tid = threadIdx.x;
    const int kbase = blockIdx.x * 64;
    const float* src = emb + (size_t)kbase * DDIM;
#pragma unroll
    for (int i = 0; i < 16; ++i) {
        int g = i * 256 + tid;
        L[(g >> 6) * ZPAD + (g & 63)] = src[g];
    }
    __syncthreads();
#pragma unroll
    for (int i = 0; i < 16; ++i) {
        int g = i * 256 + tid;
        eh[(size_t)kbase * DDIM + g] = (__half)(_Float16)(L[(g >> 6) * ZPAD + (g & 63)] * 1024.0f);
    }
    if (tid < 64) h[kbase + tid] = np_sumsq64(&L[tid * ZPAD]);
}

// K2: two-pass MFMA scan with async LDS-staged eh (dbuf, swizzled), exact rescore, epilogue
extern "C" __global__
__attribute__((amdgpu_flat_work_group_size(256, 256), amdgpu_waves_per_eu(4, 4)))
void vq_mfma_kernel(
    const float* __restrict__ z, const float* __restrict__ emb,
    const __half* __restrict__ eh_, const float* __restrict__ h_,
    float* __restrict__ out, float* __restrict__ loss, float* __restrict__ idxf)
{
    __shared__ float zrow[64 * ZPAD];              // 17.0 KB
    __shared__ float h_lds[KDIM];                  // 4 KB
    __shared__ float lds_sn[64];
    __shared__ unsigned int m1bits[64];
    __shared__ int qcnt;
    __shared__ unsigned short qk[QCAP];
    __shared__ unsigned char  qn[QCAP];
    __shared__ unsigned long long rbest[64];
    __shared__ __align__(16) char ebuf[4][2][2048]; // per-wave double-buffered eh tile, 16 KB

    const int tid = threadIdx.x, l = tid & 63, w = tid >> 6;
    const int nbase = blockIdx.x * 64;
    const int b = nbase >> 15, s0 = nbase & (SPAT - 1);
    const int col16 = l & 15, g16 = l >> 4;
    const float* zbase = z + (size_t)b * DSP + s0;

    if (tid == 0) qcnt = 0;
    if (tid < 64) { rbest[tid] = ~0ull; m1bits[tid] = 0xffffffffu; }

    // stage h (coalesced float4) and z rows
    ((float4*)h_lds)[tid] = ((const float4*)h_)[tid];
    {
        const int dbase = w * 16;
#pragma unroll
        for (int j = 0; j < 16; ++j)
            zrow[l * ZPAD + dbase + j] = zbase[(size_t)(dbase + j) * SPAT + l];
    }
    __syncthreads();

    if (tid < 64) lds_sn[tid] = np_sumsq64(&zrow[tid * ZPAD]);

    // resident Z hi fragments
    half8 zf[4][2];
#pragma unroll
    for (int nc = 0; nc < 4; ++nc) {
        const int r = nc * 16 + col16;
#pragma unroll
        for (int kp = 0; kp < 2; ++kp) {
            const int d0 = g16 * 8 + kp * 32;
            half8 vh;
#pragma unroll
            for (int u = 0; u < 8; ++u)
                vh[u] = (_Float16)zrow[r * ZPAD + d0 + u];
            zf[nc][kp] = vh;
        }
    }

    const int myk0 = w * 256;
    // pre-swizzled global source offsets (LDS dest is linear base + lane*16)
    const int swl  = ((l >> 3) & 7) << 4;
    const int src0 = (l * 16) ^ swl;
    const int src1 = 1024 + ((l * 16) ^ swl);
    // swizzled read offset for this lane's A-fragment (row col16, 16B at g16*16; ^64 for kp=1)
    const int rd0 = (col16 * 128 + g16 * 16) ^ ((col16 & 7) << 4);

#define STAGE(t, buf) { \
        const char* gsrc = (const char*)(eh_ + (size_t)(myk0 + (t) * 16) * DDIM); \
        char* db = &ebuf[w][buf][0]; \
        __builtin_amdgcn_global_load_lds((const __attribute__((address_space(1))) void*)(gsrc + src0), \
                                         (__attribute__((address_space(3))) void*)db, 16, 0, 0); \
        __builtin_amdgcn_global_load_lds((const __attribute__((address_space(1))) void*)(gsrc + src1), \
                                         (__attribute__((address_space(3))) void*)(db + 1024), 16, 0, 0); }

    // ---- pass 1: approx row min ----
    float m1[4];
#pragma unroll
    for (int nc = 0; nc < 4; ++nc) m1[nc] = 3.0e38f;
    STAGE(0, 0) STAGE(1, 1)
#pragma unroll
    for (int t = 0; t < 16; ++t) {
        const int buf = t & 1;
        if (t < 15) asm volatile("s_waitcnt vmcnt(2)" ::: "memory");
        else        asm volatile("s_waitcnt vmcnt(0)" ::: "memory");
        const char* tb = &ebuf[w][buf][0];
        half8 f0 = *(const half8*)(tb + rd0);
        half8 f1 = *(const half8*)(tb + (rd0 ^ 64));
        floatx4 hv = *(const floatx4*)(&h_lds[myk0 + t * 16 + g16 * 4]);
        asm volatile("" :: "v"((floatx4)f0), "v"((floatx4)f1));  // force ds_read completion
        if (t < 14) STAGE(t + 2, buf)
#pragma unroll
        for (int nc = 0; nc < 4; ++nc) {
            floatx4 acc = {0.f, 0.f, 0.f, 0.f};
            acc = __builtin_amdgcn_mfma_f32_16x16x32_f16(f0, zf[nc][0], acc, 0, 0, 0);
            acc = __builtin_amdgcn_mfma_f32_16x16x32_f16(f1, zf[nc][1], acc, 0, 0, 0);
#pragma unroll
            for (int j = 0; j < 4; ++j)
                m1[nc] = fminf(m1[nc], fmaf(-0.001953125f, acc[j], hv[j]));
        }
    }
#pragma unroll
    for (int nc = 0; nc < 4; ++nc)
        atomicMin(&m1bits[nc * 16 + col16], f2s(m1[nc]));
    __syncthreads();

    float thr[4];
#pragma unroll
    for (int nc = 0; nc < 4; ++nc) thr[nc] = s2f(m1bits[nc * 16 + col16]) + MARGIN;

    // ---- pass 2: re-scan, push candidates within MARGIN of row min ----
    STAGE(0, 0) STAGE(1, 1)
#pragma unroll
    for (int t = 0; t < 16; ++t) {
        const int buf = t & 1;
        if (t < 15) asm volatile("s_waitcnt vmcnt(2)" ::: "memory");
        else        asm volatile("s_waitcnt vmcnt(0)" ::: "memory");
        const char* tb = &ebuf[w][buf][0];
        half8 f0 = *(const half8*)(tb + rd0);
        half8 f1 = *(const half8*)(tb + (rd0 ^ 64));
        floatx4 hv = *(const floatx4*)(&h_lds[myk0 + t * 16 + g16 * 4]);
        asm volatile("" :: "v"((floatx4)f0), "v"((floatx4)f1));
        if (t < 14) STAGE(t + 2, buf)
        const int rbase = myk0 + t * 16 + g16 * 4;
#pragma unroll
        for (int nc = 0; nc < 4; ++nc) {
            floatx4 acc = {0.f, 0.f, 0.f, 0.f};
            acc = __builtin_amdgcn_mfma_f32_16x16x32_f16(f0, zf[nc][0], acc, 0, 0, 0);
            acc = __builtin_amdgcn_mfma_f32_16x16x32_f16(f1, zf[nc][1], acc, 0, 0, 0);
            float d0 = fmaf(-0.001953125f, acc[0], hv[0]);
            float d1 = fmaf(-0.001953125f, acc[1], hv[1]);
            float d2 = fmaf(-0.001953125f, acc[2], hv[2]);
            float d3 = fmaf(-0.001953125f, acc[3], hv[3]);
            if (__any((d0 <= thr[nc]) | (d1 <= thr[nc]) | (d2 <= thr[nc]) | (d3 <= thr[nc]))) {
#pragma unroll
                for (int j = 0; j < 4; ++j) {
                    float dj = (j == 0) ? d0 : (j == 1) ? d1 : (j == 2) ? d2 : d3;
                    if (dj <= thr[nc]) {
                        int p = atomicAdd(&qcnt, 1);
                        if (p < QCAP) {
                            qk[p] = (unsigned short)(rbase + j);
                            qn[p] = (unsigned char)(nc * 16 + col16);
                        }
                    }
                }
            }
        }
    }
#undef STAGE
    __syncthreads();

    // ---- phase 3: bit-exact numpy-f32 rescore of candidates ----
    const int qlen = min(qcnt, QCAP);
    for (int i = tid; i < qlen; i += 256) {
        const int r = qn[i];
        atomicMin(&rbest[r], exact_score(&zrow[r * ZPAD], lds_sn[r], emb, h_lds, qk[i]));
    }
    __syncthreads();

    if (qcnt > QCAP) {   // cold correctness fallback: full exact scan
        const int row = tid & 63, kq = tid >> 6;
        for (int k = kq * 256; k < kq * 256 + 256; ++k)
            atomicMin(&rbest[row], exact_score(&zrow[row * ZPAD], lds_sn[row], emb, h_lds, k));
        __syncthreads();
    }

    // ---- epilogue: idx, z_q gather (all 4 waves, coalesced per d-plane), loss ----
    if (tid < 64) idxf[nbase + tid] = (float)(unsigned int)(rbest[tid] & 0xffffffffu);
    {
        const int I1 = (int)(rbest[l] & 0xffffffffu);   // this lane's row
        const int dbase = w * 16;
        float* opb = out + (size_t)b * DSP + s0;
        float lsum = 0.f;
#pragma unroll
        for (int j = 0; j < 16; ++j) {
            const int d = dbase + j;
            float qv = emb[(size_t)I1 * DDIM + d];
            opb[(size_t)d * SPAT + l] = qv;
            float df = qv - zrow[l * ZPAD + d];
            lsum = fmaf(df, df, lsum);
        }
#pragma unroll
        for (int off = 32; off > 0; off >>= 1)
            lsum += __shfl_down(lsum, off, 64);
        if (l == 0)
            atomicAdd(loss, lsum * (1.25f / 4194304.0f));  // (beta+1)*mean
    }
}

extern "C" void kernel_launch(void* const* d_in, const int* in_sizes, int n_in,
                              void* d_out, int out_size, void* d_ws, size_t ws_size,
                              hipStream_t stream) {
    const float* z   = (const float*)d_in[0];   // [2, 64, 32, 32, 32]
    const float* emb = (const float*)d_in[1];   // [1024, 64]
    float* out  = (float*)d_out;                // z_q (4194304) | loss (1) | indices (65536)
    float* loss = out + 4194304;
    float* idxf = out + 4194305;

    float* h_  = (float*)d_ws;                  // [1024]
    __half* eh_ = (__half*)(h_ + KDIM);         // [1024*64] halves

    hipMemsetAsync(loss, 0, sizeof(float), stream);
    vq_prep_e<<<KDIM / 64, 256, 0, stream>>>(emb, h_, eh_);
    hipLaunchKernelGGL(vq_mfma_kernel, dim3(NVEC / 64), dim3(256), 0, stream,
                       z, emb, eh_, h_, out, loss, idxf);
}